// Round 1
// baseline (552.409 us; speedup 1.0000x reference)
//
#include <hip/hip_runtime.h>
#include <stdint.h>

#define HW 4096
#define NB 8
#define JB 128
#define IB 64

typedef unsigned short u16;
typedef __attribute__((ext_vector_type(8))) short bf16x8;
typedef __attribute__((ext_vector_type(4))) float f32x4;
typedef __attribute__((address_space(1))) const unsigned int g_u32;
typedef __attribute__((address_space(3))) unsigned int l_u32;

__device__ __forceinline__ u16 f2bf(float f) {
  union { float f; unsigned u; } v; v.f = f;
  unsigned r = v.u + 0x7FFFu + ((v.u >> 16) & 1u);
  return (u16)(r >> 16);
}

__device__ __forceinline__ void gld16(const void* gsrc, void* ldst) {
  __builtin_amdgcn_global_load_lds((g_u32*)(uintptr_t)gsrc, (l_u32*)(uintptr_t)ldst, 16, 0, 0);
}

__device__ __forceinline__ void wgbar() {
  asm volatile("" ::: "memory");
  __builtin_amdgcn_s_barrier();
  asm volatile("" ::: "memory");
}

// ---------- K0: W fp32 -> bf16 (row-major [o][c]) ----------
__global__ void k_wb(const float* __restrict__ W, u16* __restrict__ wb) {
  int g = blockIdx.x * 256 + threadIdx.x;   // 64 blocks -> 16384 float4
  float4 v = ((const float4*)W)[g];
  ushort4 o;
  o.x = f2bf(v.x); o.y = f2bf(v.y); o.z = f2bf(v.z); o.w = f2bf(v.w);
  ((ushort4*)wb)[g] = o;
}

// ---------- K1: per-pixel norm: inv = 1/max(||x||,eps), nrm = max(||x||,eps) ----------
__global__ void k_norms(const float* __restrict__ x, float* __restrict__ inv,
                        float* __restrict__ nrm) {
  int g = blockIdx.x * 256 + threadIdx.x;   // 128 blocks -> 32768 pixels
  int b = g >> 12, i = g & (HW - 1);
  const float* xp = x + ((size_t)b << 20) + i;
  float s = 0.f;
  #pragma unroll 8
  for (int c = 0; c < 256; ++c) {
    float v = xp[(size_t)c << 12];
    s += v * v;
  }
  float n = fmaxf(sqrtf(s), 1e-12f);
  nrm[g] = n;
  inv[g] = 1.0f / n;
}

// ---------- K2: xnt[b][i][c] = bf16(x[b][c][i] * inv[b][i])  (LDS transpose) ----------
__global__ void k_xnt(const float* __restrict__ x, const float* __restrict__ inv,
                      u16* __restrict__ xnt) {
  __shared__ u16 tile[64][72];
  int b = blockIdx.x >> 6;
  int i0 = (blockIdx.x & 63) << 6;
  int il = threadIdx.x & 63;
  int q  = threadIdx.x >> 6;     // 0..3
  float iv = inv[(b << 12) + i0 + il];
  const float* xb = x + ((size_t)b << 20);
  for (int cch = 0; cch < 4; ++cch) {
    int c0 = cch << 6;
    #pragma unroll
    for (int k = 0; k < 16; ++k) {
      int cc = q * 16 + k;
      float v = xb[((size_t)(c0 + cc) << 12) + i0 + il] * iv;
      tile[il][cc] = f2bf(v);
    }
    __syncthreads();
    int row = threadIdx.x >> 2, seg = threadIdx.x & 3;
    unsigned wv[8];
    #pragma unroll
    for (int k = 0; k < 8; ++k) {
      unsigned lo = tile[row][seg * 16 + 2 * k];
      unsigned hi = tile[row][seg * 16 + 2 * k + 1];
      wv[k] = lo | (hi << 16);
    }
    u16* dst = xnt + (((size_t)((b << 12) + i0 + row)) << 8) + c0 + seg * 16;
    uint4 p0; p0.x = wv[0]; p0.y = wv[1]; p0.z = wv[2]; p0.w = wv[3];
    uint4 p1; p1.x = wv[4]; p1.y = wv[5]; p1.z = wv[6]; p1.w = wv[7];
    ((uint4*)dst)[0] = p0;
    ((uint4*)dst)[1] = p1;
    __syncthreads();
  }
}

// ---------- K3: t[b][o][i] = bf16( nrm[i] * sum_c Wb[o][c]*xnt[i][c] + bias[o] ) ----------
__global__ __launch_bounds__(256) void k_tgemm(const u16* __restrict__ wb,
                                               const u16* __restrict__ xnt,
                                               const float* __restrict__ bias,
                                               const float* __restrict__ nrm,
                                               u16* __restrict__ t) {
  int b = blockIdx.x >> 6;
  int i0 = (blockIdx.x & 63) << 6;
  int w = threadIdx.x >> 6, l = threadIdx.x & 63;
  int lr = l & 15, lq = l >> 4;
  const u16* xb = xnt + (((size_t)((b << 12) + i0)) << 8);
  const f32x4 fz = {0.f, 0.f, 0.f, 0.f};
  f32x4 acc[4][4];
  #pragma unroll
  for (int a = 0; a < 4; ++a)
    #pragma unroll
    for (int c = 0; c < 4; ++c) acc[a][c] = fz;
  #pragma unroll 2
  for (int ks = 0; ks < 8; ++ks) {
    bf16x8 af[4], bfm[4];
    #pragma unroll
    for (int mf = 0; mf < 4; ++mf)
      af[mf] = *(const bf16x8*)(wb + ((64 * w + mf * 16 + lr) << 8) + ks * 32 + lq * 8);
    #pragma unroll
    for (int nf = 0; nf < 4; ++nf)
      bfm[nf] = *(const bf16x8*)(xb + ((nf * 16 + lr) << 8) + ks * 32 + lq * 8);
    #pragma unroll
    for (int mf = 0; mf < 4; ++mf)
      #pragma unroll
      for (int nf = 0; nf < 4; ++nf)
        acc[mf][nf] = __builtin_amdgcn_mfma_f32_16x16x32_bf16(af[mf], bfm[nf], acc[mf][nf], 0, 0, 0);
  }
  float nv[4];
  #pragma unroll
  for (int nf = 0; nf < 4; ++nf) nv[nf] = nrm[(b << 12) + i0 + nf * 16 + lr];
  #pragma unroll
  for (int mf = 0; mf < 4; ++mf) {
    int o = 64 * w + mf * 16 + lq * 4;
    #pragma unroll
    for (int r = 0; r < 4; ++r) {
      float bs = bias[o + r];
      u16* dst = t + (((size_t)((b << 8) + o + r)) << 12) + i0;
      #pragma unroll
      for (int nf = 0; nf < 4; ++nf) {
        float tv = acc[mf][nf][r] * nv[nf] + bs;
        dst[nf * 16 + lr] = f2bf(tv);
      }
    }
  }
}

// ---------- K4: fused  out[:,jblk] = sum_i t[:,iblk] * square(Xi . Xj^T) ----------
__global__ __launch_bounds__(512, 2) void k_main(const u16* __restrict__ xnt,
                                                 const u16* __restrict__ tt,
                                                 float* __restrict__ out) {
  __shared__ char smem[81920];           // Xi0 32K | Xi1 32K | PT 16K
  char* Xi0 = smem;
  char* Xi1 = smem + 32768;
  char* PT  = smem + 65536;

  int bid = blockIdx.x;
  int b = bid & 7;                       // batch -> XCD (round-robin)
  int jt = bid >> 3;
  int j0 = jt * JB;
  int tid = threadIdx.x;
  int w = tid >> 6, l = tid & 63;
  int lr = l & 15, lq = l >> 4;

  const u16* xb = xnt + ((size_t)b << 20);   // [i][c], row 256 u16
  const u16* tb = tt  + ((size_t)b << 20);   // [c][i], row 4096 u16

  int jw = w >> 1, iw = w & 1;           // stage A role: 32j x 32i
  int mw = w >> 1, nw = w & 1;           // stage B role: 64c x 64j

  // hoist Xj A-fragments (loop-invariant): rows j0+32*jw+jf*16+lr
  bf16x8 xj[2][8];
  #pragma unroll
  for (int jf = 0; jf < 2; ++jf) {
    const u16* p = xb + ((size_t)(j0 + 32 * jw + jf * 16 + lr) << 8) + lq * 8;
    #pragma unroll
    for (int ks = 0; ks < 8; ++ks)
      xj[jf][ks] = *(const bf16x8*)(p + ks * 32);
  }
  #pragma unroll
  for (int jf = 0; jf < 2; ++jf)
    #pragma unroll
    for (int ks = 0; ks < 8; ++ks)
      asm volatile("" :: "v"(xj[jf][ks]));   // pin: waitcnt for these lands here

  const f32x4 fz = {0.f, 0.f, 0.f, 0.f};
  f32x4 acc[4][4];
  #pragma unroll
  for (int a = 0; a < 4; ++a)
    #pragma unroll
    for (int c = 0; c < 4; ++c) acc[a][c] = fz;

  // Xi staging: 32 x 1KB gl_lds, 4 per wave; LDS linear, source pre-swizzled
  auto stageXi = [&](char* dstbase, int tile) {
    int i0s = (tile & 63) * IB;
    #pragma unroll
    for (int q = 0; q < 4; ++q) {
      int slot = w * 4 + q;                  // 0..31
      int r = slot * 2 + (l >> 5);           // row 0..63
      int c16 = l & 31;
      const u16* src = xb + ((size_t)(i0s + r) << 8) + ((c16 ^ (r & 7)) << 3);
      gld16(src, dstbase + slot * 1024);
    }
  };

  stageXi(Xi0, 0);
  asm volatile("s_waitcnt vmcnt(0)" ::: "memory");
  wgbar();

  for (int it = 0; it < 64; ++it) {
    char* xiC = (it & 1) ? Xi1 : Xi0;
    char* xiN = (it & 1) ? Xi0 : Xi1;
    const int i0 = it << 6;

    // Ti fragment prefetch for THIS tile (global/L1). Issued before the
    // gl_lds so the compiler's pre-stage-B wait is vmcnt(4), not vmcnt(0).
    bf16x8 tfr[4][2];
    #pragma unroll
    for (int mf = 0; mf < 4; ++mf) {
      const u16* p = tb + ((size_t)(64 * mw + mf * 16 + lr) << 12) + i0 + lq * 8;
      tfr[mf][0] = *(const bf16x8*)(p);
      tfr[mf][1] = *(const bf16x8*)(p + 32);
    }

    stageXi(xiN, it + 1);                    // prefetch next Xi tile
    asm volatile("s_waitcnt vmcnt(12)" ::: "memory");  // 8 tfr + 4 gl_lds newer
    wgbar();                                 // #1: Xi[cur] visible everywhere

    // ---- stage A: S'[32j x 32i] = Xj . Xi^T over K=256 ----
    f32x4 sacc[2][2];
    sacc[0][0] = fz; sacc[0][1] = fz; sacc[1][0] = fz; sacc[1][1] = fz;
    #pragma unroll 2
    for (int ks = 0; ks < 8; ++ks) {
      bf16x8 bfr[2];
      #pragma unroll
      for (int ifr = 0; ifr < 2; ++ifr) {
        int rrow = 32 * iw + ifr * 16 + lr;
        int c16 = ks * 4 + lq;
        bfr[ifr] = *(const bf16x8*)(xiC + rrow * 512 + ((c16 ^ (rrow & 7)) << 4));
      }
      #pragma unroll
      for (int jf = 0; jf < 2; ++jf)
        #pragma unroll
        for (int ifr = 0; ifr < 2; ++ifr)
          sacc[jf][ifr] = __builtin_amdgcn_mfma_f32_16x16x32_bf16(
              xj[jf][ks], bfr[ifr], sacc[jf][ifr], 0, 0, 0);
    }

    // square -> PT[j][i] bf16 (XOR-swizzled rows)
    #pragma unroll
    for (int jf = 0; jf < 2; ++jf) {
      #pragma unroll
      for (int ifr = 0; ifr < 2; ++ifr) {
        int icol = 32 * iw + ifr * 16 + lr;
        #pragma unroll
        for (int r = 0; r < 4; ++r) {
          int jrow = 32 * jw + jf * 16 + lq * 4 + r;
          float v = sacc[jf][ifr][r];
          v *= v;
          *(u16*)(PT + jrow * 128 + (((icol >> 3) ^ (jrow & 7)) << 4) + (icol & 7) * 2) = f2bf(v);
        }
      }
    }
    asm volatile("s_waitcnt lgkmcnt(0)" ::: "memory");
    wgbar();                                 // #2: PT visible everywhere

    // ---- stage B: acc[64c x 64j] += t_i . P ----
    #pragma unroll
    for (int ks = 0; ks < 2; ++ks) {
      bf16x8 pfr[4];
      #pragma unroll
      for (int nf = 0; nf < 4; ++nf) {
        int nrow = 64 * nw + nf * 16 + lr;
        int c16 = ks * 4 + lq;
        pfr[nf] = *(const bf16x8*)(PT + nrow * 128 + ((c16 ^ (nrow & 7)) << 4));
      }
      #pragma unroll
      for (int mf = 0; mf < 4; ++mf)
        #pragma unroll
        for (int nf = 0; nf < 4; ++nf)
          acc[mf][nf] = __builtin_amdgcn_mfma_f32_16x16x32_bf16(
              tfr[mf][ks], pfr[nf], acc[mf][nf], 0, 0, 0);
    }
  }

  // epilogue: out[b][c][j] fp32
  #pragma unroll
  for (int mf = 0; mf < 4; ++mf) {
    int cc = 64 * mw + mf * 16 + lq * 4;
    #pragma unroll
    for (int nf = 0; nf < 4; ++nf) {
      int j = j0 + 64 * nw + nf * 16 + lr;
      float* dst = out + (((size_t)((b << 8) + cc)) << 12) + j;
      #pragma unroll
      for (int r = 0; r < 4; ++r)
        dst[((size_t)r) << 12] = acc[mf][nf][r];
    }
  }
}

extern "C" void kernel_launch(void* const* d_in, const int* in_sizes, int n_in,
                              void* d_out, int out_size, void* d_ws, size_t ws_size,
                              hipStream_t stream) {
  const float* x    = (const float*)d_in[0];
  const float* W    = (const float*)d_in[1];
  const float* bias = (const float*)d_in[2];
  float* out = (float*)d_out;

  char* ws = (char*)d_ws;
  u16*   xnt = (u16*)(ws);                                  // 16 MiB  [b][i][c] bf16
  u16*   tt  = (u16*)(ws + ((size_t)16 << 20));             // 16 MiB  [b][c][i] bf16
  u16*   wb  = (u16*)(ws + ((size_t)32 << 20));             // 128 KiB
  float* inv = (float*)(ws + ((size_t)33 << 20));           // 128 KiB
  float* nrm = (float*)(ws + ((size_t)34 << 20));           // 128 KiB

  hipLaunchKernelGGL(k_wb,    dim3(64),  dim3(256), 0, stream, W, wb);
  hipLaunchKernelGGL(k_norms, dim3(128), dim3(256), 0, stream, x, inv, nrm);
  hipLaunchKernelGGL(k_xnt,   dim3(512), dim3(256), 0, stream, x, inv, xnt);
  hipLaunchKernelGGL(k_tgemm, dim3(512), dim3(256), 0, stream, wb, xnt, bias, nrm, tt);
  hipLaunchKernelGGL(k_main,  dim3(256), dim3(512), 0, stream, xnt, tt, out);
}

// Round 2
// 451.909 us; speedup vs baseline: 1.2224x; 1.2224x over previous
//
#include <hip/hip_runtime.h>
#include <stdint.h>

#define HW 4096

typedef unsigned short u16;
typedef unsigned int u32;
typedef __attribute__((ext_vector_type(8))) short bf16x8;
typedef __attribute__((ext_vector_type(4))) float f32x4;

__device__ __forceinline__ u16 f2bf(float f) {
  union { float f; unsigned u; } v; v.f = f;
  unsigned r = v.u + 0x7FFFu + ((v.u >> 16) & 1u);
  return (u16)(r >> 16);
}

// ---------- K0: W fp32 -> bf16 (row-major [o][c]) ----------
__global__ void k_wb(const float* __restrict__ W, u16* __restrict__ wb) {
  int g = blockIdx.x * 256 + threadIdx.x;   // 64 blocks -> 16384 float4
  float4 v = ((const float4*)W)[g];
  ushort4 o;
  o.x = f2bf(v.x); o.y = f2bf(v.y); o.z = f2bf(v.z); o.w = f2bf(v.w);
  ((ushort4*)wb)[g] = o;
}

// ---------- K1: fused norm + transpose:
//   nrm[b][i] = max(||x[b][:][i]||, eps);  xnt[b][i][c] = bf16(x[b][c][i]/nrm) ----------
__global__ void k_xnt(const float* __restrict__ x, u16* __restrict__ xnt,
                      float* __restrict__ nrm) {
  __shared__ u16 tile[64][72];
  __shared__ float part[4][64];
  __shared__ float invs[64];
  int b = blockIdx.x >> 6;
  int i0 = (blockIdx.x & 63) << 6;
  int il = threadIdx.x & 63;
  int q  = threadIdx.x >> 6;     // wave id 0..3
  const float* xb = x + ((size_t)b << 20);
  // pass 1: sum of squares over channels (wave q covers c = 64q..64q+63)
  float s = 0.f;
  #pragma unroll 8
  for (int k = 0; k < 64; ++k) {
    float v = xb[((size_t)(q * 64 + k) << 12) + i0 + il];
    s += v * v;
  }
  part[q][il] = s;
  __syncthreads();
  if (q == 0) {
    float tot = part[0][il] + part[1][il] + part[2][il] + part[3][il];
    float n = fmaxf(sqrtf(tot), 1e-12f);
    nrm[(b << 12) + i0 + il] = n;
    invs[il] = 1.0f / n;
  }
  __syncthreads();
  float iv = invs[il];
  // pass 2: transpose + scale (x re-read is L2-hot)
  for (int cch = 0; cch < 4; ++cch) {
    int c0 = cch << 6;
    #pragma unroll
    for (int k = 0; k < 16; ++k) {
      int cc = q * 16 + k;
      float v = xb[((size_t)(c0 + cc) << 12) + i0 + il] * iv;
      tile[il][cc] = f2bf(v);
    }
    __syncthreads();
    int row = threadIdx.x >> 2, seg = threadIdx.x & 3;
    unsigned wv[8];
    #pragma unroll
    for (int k = 0; k < 8; ++k) {
      unsigned lo = tile[row][seg * 16 + 2 * k];
      unsigned hi = tile[row][seg * 16 + 2 * k + 1];
      wv[k] = lo | (hi << 16);
    }
    u16* dst = xnt + (((size_t)((b << 12) + i0 + row)) << 8) + c0 + seg * 16;
    uint4 p0; p0.x = wv[0]; p0.y = wv[1]; p0.z = wv[2]; p0.w = wv[3];
    uint4 p1; p1.x = wv[4]; p1.y = wv[5]; p1.z = wv[6]; p1.w = wv[7];
    ((uint4*)dst)[0] = p0;
    ((uint4*)dst)[1] = p1;
    __syncthreads();
  }
}

// ---------- K2: t[b][o][i] = bf16( nrm[i] * sum_c Wb[o][c]*xnt[i][c] + bias[o] ) ----------
__global__ __launch_bounds__(256) void k_tgemm(const u16* __restrict__ wb,
                                               const u16* __restrict__ xnt,
                                               const float* __restrict__ bias,
                                               const float* __restrict__ nrm,
                                               u16* __restrict__ t) {
  int b = blockIdx.x >> 6;
  int i0 = (blockIdx.x & 63) << 6;
  int w = threadIdx.x >> 6, l = threadIdx.x & 63;
  int lr = l & 15, lq = l >> 4;
  const u16* xb = xnt + (((size_t)((b << 12) + i0)) << 8);
  const f32x4 fz = {0.f, 0.f, 0.f, 0.f};
  f32x4 acc[4][4];
  #pragma unroll
  for (int a = 0; a < 4; ++a)
    #pragma unroll
    for (int c = 0; c < 4; ++c) acc[a][c] = fz;
  #pragma unroll 2
  for (int ks = 0; ks < 8; ++ks) {
    bf16x8 af[4], bfm[4];
    #pragma unroll
    for (int mf = 0; mf < 4; ++mf)
      af[mf] = *(const bf16x8*)(wb + ((64 * w + mf * 16 + lr) << 8) + ks * 32 + lq * 8);
    #pragma unroll
    for (int nf = 0; nf < 4; ++nf)
      bfm[nf] = *(const bf16x8*)(xb + ((nf * 16 + lr) << 8) + ks * 32 + lq * 8);
    #pragma unroll
    for (int mf = 0; mf < 4; ++mf)
      #pragma unroll
      for (int nf = 0; nf < 4; ++nf)
        acc[mf][nf] = __builtin_amdgcn_mfma_f32_16x16x32_bf16(af[mf], bfm[nf], acc[mf][nf], 0, 0, 0);
  }
  float nv[4];
  #pragma unroll
  for (int nf = 0; nf < 4; ++nf) nv[nf] = nrm[(b << 12) + i0 + nf * 16 + lr];
  #pragma unroll
  for (int mf = 0; mf < 4; ++mf) {
    int o = 64 * w + mf * 16 + lq * 4;
    #pragma unroll
    for (int r = 0; r < 4; ++r) {
      float bs = bias[o + r];
      u16* dst = t + (((size_t)((b << 8) + o + r)) << 12) + i0;
      #pragma unroll
      for (int nf = 0; nf < 4; ++nf) {
        float tv = acc[mf][nf][r] * nv[nf] + bs;
        dst[nf * 16 + lr] = f2bf(tv);
      }
    }
  }
}

// ---------- K3: fused  out[:, jblk] = sum_i t[:, iblk] * square(S^T)  ----------
// 4 waves (256 thr), JB=64, IB=64, grid 512 = 2 blocks/CU.
// QK swapped: mfma(Xi, Xj) -> D[i][j]: lane holds 4 consecutive i for fixed j
//   -> square+pack in-register -> one ds_write_b64 per fragment (swizzled).
// ONE barrier per tile (PT handoff only, double-buffered); Xi/t frags from
// global (L1/L2-resident per XCD), no vmcnt drain at the barrier.
__global__ __launch_bounds__(256, 2) void k_main(const u16* __restrict__ xnt,
                                                 const u16* __restrict__ tt,
                                                 float* __restrict__ out) {
  __shared__ __align__(16) u16 PT[2][4096];   // 2 x 8 KB, 16B-unit XOR-swizzled
  int bid = blockIdx.x;
  int b = bid & 7;                            // batch -> XCD (round-robin)
  int jt = bid >> 3;
  int j0 = jt << 6;
  int tid = threadIdx.x;
  int w = tid >> 6, l = tid & 63;
  int lr = l & 15, lq = l >> 4;
  int jw = w >> 1, iww = w & 1;               // stage A: 32j x 32i per wave
  // stage B: wave w owns c-range 64w, all 64 j

  const u16* xb = xnt + ((size_t)b << 20);    // [i][c], row 256 u16
  const u16* tb = tt  + ((size_t)b << 20);    // [c][i], row 4096 u16

  // hoist Xj B-fragments (loop-invariant): cols j0+32*jw+jf*16+lr
  bf16x8 xj[2][8];
  #pragma unroll
  for (int jf = 0; jf < 2; ++jf) {
    const u16* p = xb + ((size_t)(j0 + 32 * jw + jf * 16 + lr) << 8) + lq * 8;
    #pragma unroll
    for (int ks = 0; ks < 8; ++ks)
      xj[jf][ks] = *(const bf16x8*)(p + ks * 32);
  }
  #pragma unroll
  for (int jf = 0; jf < 2; ++jf)
    #pragma unroll
    for (int ks = 0; ks < 8; ++ks)
      asm volatile("" :: "v"(xj[jf][ks]));

  const f32x4 fz = {0.f, 0.f, 0.f, 0.f};
  f32x4 acc[4][4];
  #pragma unroll
  for (int a = 0; a < 4; ++a)
    #pragma unroll
    for (int c = 0; c < 4; ++c) acc[a][c] = fz;

  for (int it = 0; it < 64; ++it) {
    const int i0 = it << 6;
    u16* pt = &PT[it & 1][0];

    // t-fragments for stage B: issue early, stay in flight across the barrier
    bf16x8 tfr[4][2];
    #pragma unroll
    for (int mf = 0; mf < 4; ++mf) {
      const u16* pB = tb + ((size_t)(64 * w + mf * 16 + lr) << 12) + i0 + lq * 8;
      tfr[mf][0] = *(const bf16x8*)(pB);
      tfr[mf][1] = *(const bf16x8*)(pB + 32);
    }

    // ---- stage A: D[i][j] = Xi . Xj^T (swapped), K=256 ----
    f32x4 sacc[2][2];
    sacc[0][0] = fz; sacc[0][1] = fz; sacc[1][0] = fz; sacc[1][1] = fz;
    #pragma unroll
    for (int if_ = 0; if_ < 2; ++if_) {
      bf16x8 bfr[8];
      const u16* pA = xb + ((size_t)(i0 + iww * 32 + if_ * 16 + lr) << 8) + lq * 8;
      #pragma unroll
      for (int ks = 0; ks < 8; ++ks) bfr[ks] = *(const bf16x8*)(pA + ks * 32);
      #pragma unroll
      for (int ks = 0; ks < 8; ++ks) {
        sacc[0][if_] = __builtin_amdgcn_mfma_f32_16x16x32_bf16(bfr[ks], xj[0][ks], sacc[0][if_], 0, 0, 0);
        sacc[1][if_] = __builtin_amdgcn_mfma_f32_16x16x32_bf16(bfr[ks], xj[1][ks], sacc[1][if_], 0, 0, 0);
      }
    }

    // square + pack 4 consecutive i -> one b64 write per fragment (swizzled)
    #pragma unroll
    for (int jf = 0; jf < 2; ++jf) {
      #pragma unroll
      for (int if_ = 0; if_ < 2; ++if_) {
        f32x4 s = sacc[jf][if_];
        u32 w0 = (u32)f2bf(s[0] * s[0]) | ((u32)f2bf(s[1] * s[1]) << 16);
        u32 w1 = (u32)f2bf(s[2] * s[2]) | ((u32)f2bf(s[3] * s[3]) << 16);
        int jrow = jw * 32 + jf * 16 + lr;
        int unit = 4 * iww + 2 * if_ + (lq >> 1);
        int off = jrow * 128 + ((unit ^ (jrow & 7)) << 4) + ((lq & 1) << 3);
        uint2 val; val.x = w0; val.y = w1;
        *(uint2*)((char*)pt + off) = val;
      }
    }

    asm volatile("s_waitcnt lgkmcnt(0)" ::: "memory");  // PT writes landed (vmcnt stays in flight)
    __builtin_amdgcn_sched_barrier(0);
    __builtin_amdgcn_s_barrier();
    __builtin_amdgcn_sched_barrier(0);

    // ---- stage B: acc[64c x 64j] += t_i . P ----
    #pragma unroll
    for (int ks = 0; ks < 2; ++ks) {
      bf16x8 pfr[4];
      #pragma unroll
      for (int nf = 0; nf < 4; ++nf) {
        int jr = nf * 16 + lr;
        int off = jr * 128 + ((((ks << 2) + lq) ^ (jr & 7)) << 4);
        pfr[nf] = *(const bf16x8*)((const char*)pt + off);
      }
      #pragma unroll
      for (int mf = 0; mf < 4; ++mf)
        #pragma unroll
        for (int nf = 0; nf < 4; ++nf)
          acc[mf][nf] = __builtin_amdgcn_mfma_f32_16x16x32_bf16(tfr[mf][ks], pfr[nf], acc[mf][nf], 0, 0, 0);
    }
  }

  // epilogue: out[b][c][j] fp32, coalesced 64B segments
  #pragma unroll
  for (int mf = 0; mf < 4; ++mf) {
    int c = (b << 8) + 64 * w + mf * 16 + lq * 4;
    #pragma unroll
    for (int nf = 0; nf < 4; ++nf) {
      int j = j0 + nf * 16 + lr;
      float* dst = out + ((size_t)c << 12) + j;
      #pragma unroll
      for (int r = 0; r < 4; ++r)
        dst[(size_t)r << 12] = acc[mf][nf][r];
    }
  }
}

extern "C" void kernel_launch(void* const* d_in, const int* in_sizes, int n_in,
                              void* d_out, int out_size, void* d_ws, size_t ws_size,
                              hipStream_t stream) {
  const float* x    = (const float*)d_in[0];
  const float* W    = (const float*)d_in[1];
  const float* bias = (const float*)d_in[2];
  float* out = (float*)d_out;

  char* ws = (char*)d_ws;
  u16*   xnt = (u16*)(ws);                                  // 16 MiB  [b][i][c] bf16
  u16*   tt  = (u16*)(ws + ((size_t)16 << 20));             // 16 MiB  [b][c][i] bf16
  u16*   wb  = (u16*)(ws + ((size_t)32 << 20));             // 128 KiB
  float* nrm = (float*)(ws + ((size_t)33 << 20));           // 128 KiB

  hipLaunchKernelGGL(k_wb,    dim3(64),  dim3(256), 0, stream, W, wb);
  hipLaunchKernelGGL(k_xnt,   dim3(512), dim3(256), 0, stream, x, xnt, nrm);
  hipLaunchKernelGGL(k_tgemm, dim3(512), dim3(256), 0, stream, wb, xnt, bias, nrm, tt);
  hipLaunchKernelGGL(k_main,  dim3(512), dim3(256), 0, stream, xnt, tt, out);
}

// Round 6
// 355.705 us; speedup vs baseline: 1.5530x; 1.2705x over previous
//
#include <hip/hip_runtime.h>
#include <stdint.h>

#define HW 4096

typedef unsigned short u16;
typedef unsigned int u32;
typedef __attribute__((ext_vector_type(8))) short bf16x8;
typedef __attribute__((ext_vector_type(4))) float f32x4;
typedef __attribute__((address_space(1))) const unsigned int g_u32;
typedef __attribute__((address_space(3))) unsigned int l_u32;

__device__ __forceinline__ u16 f2bf(float f) {
  union { float f; unsigned u; } v; v.f = f;
  unsigned r = v.u + 0x7FFFu + ((v.u >> 16) & 1u);
  return (u16)(r >> 16);
}

__device__ __forceinline__ void gld16(const void* gsrc, void* ldst) {
  __builtin_amdgcn_global_load_lds((g_u32*)(uintptr_t)gsrc, (l_u32*)(uintptr_t)ldst, 16, 0, 0);
}

// ---------- K0: W fp32 -> bf16 (row-major [o][c]) ----------
__global__ void k_wb(const float* __restrict__ W, u16* __restrict__ wb) {
  int g = blockIdx.x * 256 + threadIdx.x;
  float4 v = ((const float4*)W)[g];
  ushort4 o;
  o.x = f2bf(v.x); o.y = f2bf(v.y); o.z = f2bf(v.z); o.w = f2bf(v.w);
  ((ushort4*)wb)[g] = o;
}

// ---------- K1: fused norm + transpose, x read from HBM ONCE via LDS stash ----------
__global__ __launch_bounds__(256) void k_xnt(const float* __restrict__ x,
                                             u16* __restrict__ xnt,
                                             float* __restrict__ nrm) {
  __shared__ float xs[256][65];     // 66.6 KB, pad 65: pass-2 reads conflict-free
  __shared__ float part[4][64];
  __shared__ float invs[64];
  int b = blockIdx.x >> 6;
  int i0 = (blockIdx.x & 63) << 6;
  int il = threadIdx.x & 63;
  int q  = threadIdx.x >> 6;
  const float* xb = x + ((size_t)b << 20);
  float s = 0.f;
  #pragma unroll 8
  for (int k = 0; k < 64; ++k) {
    int c = q * 64 + k;
    float v = xb[((size_t)c << 12) + i0 + il];
    xs[c][il] = v;
    s += v * v;
  }
  part[q][il] = s;
  __syncthreads();
  if (q == 0) {
    float tot = part[0][il] + part[1][il] + part[2][il] + part[3][il];
    float n = fmaxf(sqrtf(tot), 1e-12f);
    nrm[(b << 12) + i0 + il] = n;
    invs[il] = 1.0f / n;
  }
  __syncthreads();
  float iv = invs[il];
  // pass 2 from LDS: wave q -> c-seg [64q,64q+64), lane il -> output row i0+il
  u16* dst = xnt + (((size_t)((b << 12) + i0 + il)) << 8) + q * 64;
  #pragma unroll
  for (int h = 0; h < 8; ++h) {     // 8 c per chunk -> one uint4 store
    u32 wv[4];
    #pragma unroll
    for (int e = 0; e < 4; ++e) {
      float lo = xs[q * 64 + h * 8 + 2 * e][il] * iv;
      float hi = xs[q * 64 + h * 8 + 2 * e + 1][il] * iv;
      wv[e] = (u32)f2bf(lo) | ((u32)f2bf(hi) << 16);
    }
    uint4 p; p.x = wv[0]; p.y = wv[1]; p.z = wv[2]; p.w = wv[3];
    *(uint4*)(dst + h * 8) = p;
  }
}

// ---------- K2: t[b][o][i] = bf16( nrm[i] * sum_c Wb[o][c]*xnt[i][c] + bias[o] ) ----------
__global__ __launch_bounds__(256) void k_tgemm(const u16* __restrict__ wb,
                                               const u16* __restrict__ xnt,
                                               const float* __restrict__ bias,
                                               const float* __restrict__ nrm,
                                               u16* __restrict__ t) {
  int b = blockIdx.x >> 6;
  int i0 = (blockIdx.x & 63) << 6;
  int w = threadIdx.x >> 6, l = threadIdx.x & 63;
  int lr = l & 15, lq = l >> 4;
  const u16* xb = xnt + (((size_t)((b << 12) + i0)) << 8);
  const f32x4 fz = {0.f, 0.f, 0.f, 0.f};
  f32x4 acc[4][4];
  #pragma unroll
  for (int a = 0; a < 4; ++a)
    #pragma unroll
    for (int c = 0; c < 4; ++c) acc[a][c] = fz;
  #pragma unroll 2
  for (int ks = 0; ks < 8; ++ks) {
    bf16x8 af[4], bfm[4];
    #pragma unroll
    for (int mf = 0; mf < 4; ++mf)
      af[mf] = *(const bf16x8*)(wb + ((64 * w + mf * 16 + lr) << 8) + ks * 32 + lq * 8);
    #pragma unroll
    for (int nf = 0; nf < 4; ++nf)
      bfm[nf] = *(const bf16x8*)(xb + ((nf * 16 + lr) << 8) + ks * 32 + lq * 8);
    #pragma unroll
    for (int mf = 0; mf < 4; ++mf)
      #pragma unroll
      for (int nf = 0; nf < 4; ++nf)
        acc[mf][nf] = __builtin_amdgcn_mfma_f32_16x16x32_bf16(af[mf], bfm[nf], acc[mf][nf], 0, 0, 0);
  }
  float nv[4];
  #pragma unroll
  for (int nf = 0; nf < 4; ++nf) nv[nf] = nrm[(b << 12) + i0 + nf * 16 + lr];
  #pragma unroll
  for (int mf = 0; mf < 4; ++mf) {
    int o = 64 * w + mf * 16 + lq * 4;
    #pragma unroll
    for (int r = 0; r < 4; ++r) {
      float bs = bias[o + r];
      u16* dst = t + (((size_t)((b << 8) + o + r)) << 12) + i0;
      #pragma unroll
      for (int nf = 0; nf < 4; ++nf) {
        float tv = acc[mf][nf][r] * nv[nf] + bs;
        dst[nf * 16 + lr] = f2bf(tv);
      }
    }
  }
}

// ---------- K3: fused  out[:, jblk(128)] = sum_i t[:, i(64)] * square(S^T) ----------
// 512 thr / 8 waves, grid 256. Xi LDS-staged (gl_lds, pre-swizzled src), xj
// pinned in regs, t direct from L2 (issued first -> counted vmcnt), PT
// double-buffered. 2 barriers/tile: lgkm-only + (free) vmcnt drain.
__global__ __launch_bounds__(512, 2) void k_main(const u16* __restrict__ xnt,
                                                 const u16* __restrict__ tt,
                                                 float* __restrict__ out) {
  __shared__ __align__(16) char lds[98304];  // Xi0 32K | Xi1 32K | PT0 16K | PT1 16K
  char* XiB[2]; XiB[0] = lds; XiB[1] = lds + 32768;
  char* PTB[2]; PTB[0] = lds + 65536; PTB[1] = lds + 81920;

  int bid = blockIdx.x;
  int b = bid & 7;                           // batch -> XCD round-robin
  int jt = bid >> 3;
  int j0 = jt << 7;                          // JB = 128
  int tid = threadIdx.x;
  int w = tid >> 6, l = tid & 63;
  int lr = l & 15, lq = l >> 4;
  int iwA = w & 1, jwA = w >> 1;             // stage A: [32i x 32j] per wave
  int cw = w >> 1, jw2 = w & 1;              // stage B: [64c x 64j] per wave

  const u16* xb = xnt + ((size_t)b << 20);   // [i][c] row 256 u16
  const u16* tb = tt  + ((size_t)b << 20);   // [c][i] row 4096 u16

  // loop-invariant Xj B-fragments: strip j0 + 32*jwA (32 j), 64 VGPRs
  bf16x8 xj[2][8];
  #pragma unroll
  for (int jf = 0; jf < 2; ++jf) {
    const u16* p = xb + ((size_t)(j0 + 32 * jwA + jf * 16 + lr) << 8) + lq * 8;
    #pragma unroll
    for (int ks = 0; ks < 8; ++ks)
      xj[jf][ks] = *(const bf16x8*)(p + ks * 32);
  }

  const f32x4 fz = {0.f, 0.f, 0.f, 0.f};
  f32x4 acc[4][4];
  #pragma unroll
  for (int a = 0; a < 4; ++a)
    #pragma unroll
    for (int c = 0; c < 4; ++c) acc[a][c] = fz;

  // Xi staging: 32 slots x 1KB; LDS linear, global source pre-swizzled so a
  // read at unit (u ^ (row&7)) returns logical unit u  (T2 via m173 pattern)
  auto stageXi = [&](char* dstbase, int tile) {
    int i0s = (tile & 63) << 6;
    #pragma unroll
    for (int q2 = 0; q2 < 4; ++q2) {
      int slot = w * 4 + q2;                 // 0..31
      int r = slot * 2 + (l >> 5);           // row 0..63
      const u16* src = xb + ((size_t)(i0s + r) << 8) + (((l & 31) ^ (r & 7)) << 3);
      gld16(src, dstbase + slot * 1024);
    }
  };

  stageXi(XiB[0], 0);
  asm volatile("s_waitcnt vmcnt(0)" ::: "memory");
  __builtin_amdgcn_s_barrier();

  for (int it = 0; it < 64; ++it) {
    const int cur = it & 1;
    const int i0 = it << 6;
    char* xiC = XiB[cur];
    char* ptC = PTB[cur];

    // pin xj: loop-carried -> compiler cannot rematerialize the loads
    #pragma unroll
    for (int jf = 0; jf < 2; ++jf)
      #pragma unroll
      for (int ks = 0; ks < 8; ++ks)
        asm volatile("" : "+v"(xj[jf][ks]));

    // t-fragments for stage B — issued FIRST so their wait is vmcnt(4)
    bf16x8 tfr[4][2];
    #pragma unroll
    for (int mf = 0; mf < 4; ++mf) {
      const u16* pB = tb + ((size_t)(cw * 64 + mf * 16 + lr) << 12) + i0 + lq * 8;
      tfr[mf][0] = *(const bf16x8*)(pB);
      tfr[mf][1] = *(const bf16x8*)(pB + 32);
    }

    stageXi(XiB[cur ^ 1], it + 1);           // prefetch next Xi tile (4 gl_lds)

    // ---- stage A: D[i][j] = Xi . Xj^T, K=256, from LDS ----
    f32x4 sacc[2][2];
    sacc[0][0] = fz; sacc[0][1] = fz; sacc[1][0] = fz; sacc[1][1] = fz;
    __builtin_amdgcn_s_setprio(1);
    #pragma unroll
    for (int if_ = 0; if_ < 2; ++if_) {
      int row = iwA * 32 + if_ * 16 + lr;
      const char* base = xiC + row * 512;
      int rx = row & 7;
      bf16x8 bfr[8];
      #pragma unroll
      for (int ks = 0; ks < 8; ++ks)
        bfr[ks] = *(const bf16x8*)(base + (((ks * 4 + lq) ^ rx) << 4));
      #pragma unroll
      for (int ks = 0; ks < 8; ++ks) {
        sacc[if_][0] = __builtin_amdgcn_mfma_f32_16x16x32_bf16(bfr[ks], xj[0][ks], sacc[if_][0], 0, 0, 0);
        sacc[if_][1] = __builtin_amdgcn_mfma_f32_16x16x32_bf16(bfr[ks], xj[1][ks], sacc[if_][1], 0, 0, 0);
      }
    }
    __builtin_amdgcn_s_setprio(0);

    // square + pack 4 consecutive i -> one ds_write_b64 per fragment (swizzled)
    #pragma unroll
    for (int if_ = 0; if_ < 2; ++if_) {
      #pragma unroll
      for (int jf = 0; jf < 2; ++jf) {
        f32x4 s = sacc[if_][jf];
        u32 w0 = (u32)f2bf(s[0] * s[0]) | ((u32)f2bf(s[1] * s[1]) << 16);
        u32 w1 = (u32)f2bf(s[2] * s[2]) | ((u32)f2bf(s[3] * s[3]) << 16);
        int jrow = jwA * 32 + jf * 16 + lr;
        int u = iwA * 4 + if_ * 2 + (lq >> 1);
        int off = jrow * 128 + (((u ^ (jrow & 7))) << 4) + ((lq & 1) << 3);
        uint2 val; val.x = w0; val.y = w1;
        *(uint2*)(ptC + off) = val;
      }
    }

    asm volatile("s_waitcnt lgkmcnt(0)" ::: "memory");
    __builtin_amdgcn_sched_barrier(0);
    __builtin_amdgcn_s_barrier();            // #1: PT[cur] ready
    __builtin_amdgcn_sched_barrier(0);

    // ---- stage B: acc[64c x 64j] += t_i . P ----
    __builtin_amdgcn_s_setprio(1);
    #pragma unroll
    for (int ks = 0; ks < 2; ++ks) {
      bf16x8 pfr[4];
      #pragma unroll
      for (int nf = 0; nf < 4; ++nf) {
        int jr = jw2 * 64 + nf * 16 + lr;
        int off = jr * 128 + ((((ks << 2) + lq) ^ (jr & 7)) << 4);
        pfr[nf] = *(const bf16x8*)(ptC + off);
      }
      #pragma unroll
      for (int mf = 0; mf < 4; ++mf)
        #pragma unroll
        for (int nf = 0; nf < 4; ++nf)
          acc[mf][nf] = __builtin_amdgcn_mfma_f32_16x16x32_bf16(tfr[mf][ks], pfr[nf], acc[mf][nf], 0, 0, 0);
    }
    __builtin_amdgcn_s_setprio(0);

    asm volatile("s_waitcnt vmcnt(0)" ::: "memory");  // gl_lds issued ~a tile ago: free
    __builtin_amdgcn_sched_barrier(0);
    __builtin_amdgcn_s_barrier();            // #2: Xi[next] ready
    __builtin_amdgcn_sched_barrier(0);
  }

  // epilogue: out[b][c][j0+j] fp32
  #pragma unroll
  for (int mf = 0; mf < 4; ++mf) {
    int c = (b << 8) + cw * 64 + mf * 16 + lq * 4;
    #pragma unroll
    for (int nf = 0; nf < 4; ++nf) {
      int j = j0 + jw2 * 64 + nf * 16 + lr;
      float* dst = out + ((size_t)c << 12) + j;
      #pragma unroll
      for (int r = 0; r < 4; ++r)
        dst[(size_t)r << 12] = acc[mf][nf][r];
    }
  }
}

extern "C" void kernel_launch(void* const* d_in, const int* in_sizes, int n_in,
                              void* d_out, int out_size, void* d_ws, size_t ws_size,
                              hipStream_t stream) {
  const float* x    = (const float*)d_in[0];
  const float* W    = (const float*)d_in[1];
  const float* bias = (const float*)d_in[2];
  float* out = (float*)d_out;

  char* ws = (char*)d_ws;
  u16*   xnt = (u16*)(ws);                                  // 16 MiB  [b][i][c] bf16
  u16*   tt  = (u16*)(ws + ((size_t)16 << 20));             // 16 MiB  [b][c][i] bf16
  u16*   wb  = (u16*)(ws + ((size_t)32 << 20));             // 128 KiB
  float* nrm = (float*)(ws + ((size_t)33 << 20));           // 128 KiB

  hipLaunchKernelGGL(k_wb,    dim3(64),  dim3(256), 0, stream, W, wb);
  hipLaunchKernelGGL(k_xnt,   dim3(512), dim3(256), 0, stream, x, xnt, nrm);
  hipLaunchKernelGGL(k_tgemm, dim3(512), dim3(256), 0, stream, wb, xnt, bias, nrm, tt);
  hipLaunchKernelGGL(k_main,  dim3(256), dim3(512), 0, stream, xnt, tt, out);
}